// Round 1
// baseline (750.470 us; speedup 1.0000x reference)
//
#include <hip/hip_runtime.h>

// GRU-like fused pointwise-conv cell on MI355X (gfx950).
// B=32, C=64, H=64, L=32768. fp32 in/out; split-bf16 (hi+lo) MFMA internally.

typedef short s16x4 __attribute__((ext_vector_type(4)));
typedef short s16x8 __attribute__((ext_vector_type(8)));
typedef float f32x4 __attribute__((ext_vector_type(4)));

#define L_TOT 32768
#define LT 64          // l-points per workgroup

__device__ __forceinline__ short f2bf(float f) {
  union { float f; unsigned u; } v; v.f = f;
  unsigned r = v.u + 0x7fffu + ((v.u >> 16) & 1u);  // round-nearest-even
  return (short)(r >> 16);
}
__device__ __forceinline__ float bf2f(short s) {
  union { unsigned u; float f; } v; v.u = ((unsigned)(unsigned short)s) << 16;
  return v.f;
}
__device__ __forceinline__ float sigmoid_f(float x) {
  return 1.0f / (1.0f + __expf(-x));
}
__device__ __forceinline__ float tanh_f(float x) {
  x = fminf(fmaxf(x, -20.0f), 20.0f);
  float e = __expf(2.0f * x);
  return (e - 1.0f) / (e + 1.0f);
}

// Split W_r / W_u / W_h (each [64][128] fp32) into bf16 hi/lo arrays [192][128].
__global__ __launch_bounds__(256) void prep_weights(
    const float* __restrict__ Wr, const float* __restrict__ Wu,
    const float* __restrict__ Wh, short* __restrict__ whi,
    short* __restrict__ wlo) {
  int i = blockIdx.x * 256 + threadIdx.x;
  if (i >= 192 * 128) return;
  int r = i >> 7, c = i & 127;
  const float* src = (r < 64) ? Wr : ((r < 128) ? Wu : Wh);
  float w = src[((r & 63) << 7) | c];
  short hi = f2bf(w);
  whi[i] = hi;
  wlo[i] = f2bf(w - bf2f(hi));
}

// Swizzled LDS index (bf16-element units). Rows of 128 bf16 = 16 slots of 16B;
// XOR slot with (l&15) to spread the K-contiguous fragment reads across banks.
__device__ __forceinline__ int xt_idx(int l, int c) {
  return l * 128 + ((((c >> 3) ^ l) & 15) << 3) + (c & 7);
}
// HR buffer: rows of 64 bf16 = 8 slots of 16B.
__device__ __forceinline__ int hr_idx(int l, int c) {
  return l * 64 + ((((c >> 3) ^ l) & 7) << 3) + (c & 7);
}

#define MFMA(a, b, c) __builtin_amdgcn_mfma_f32_16x16x32_bf16(a, b, c, 0, 0, 0)

__global__ __launch_bounds__(256, 3) void gru_main(
    const float* __restrict__ xin, const float* __restrict__ hin,
    const short* __restrict__ whi, const short* __restrict__ wlo,
    const float* __restrict__ pbr, const float* __restrict__ pbu,
    const float* __restrict__ pbh, float* __restrict__ out) {
  __shared__ __align__(16) short xt_hi[64 * 128];
  __shared__ __align__(16) short xt_lo[64 * 128];
  __shared__ __align__(16) short hr_hi[64 * 64];
  __shared__ __align__(16) short hr_lo[64 * 64];

  const int tid = threadIdx.x;
  const int lane = tid & 63;
  const int wv = tid >> 6;        // wave 0..3 -> o-tile
  const int rA = lane & 15;       // MFMA row (A) / col (B,D)
  const int g8 = (lane >> 4) << 3; // k-group offset *8
  const int l0 = blockIdx.x * LT;
  const int b = blockIdx.y;

  const float* xb = xin + (size_t)b * 64 * L_TOT + l0;
  const float* hb = hin + (size_t)b * 64 * L_TOT + l0;

  // ---- Phase 1: stage X = [input; h] transposed [l][c], bf16 hi/lo split ----
  {
    const int l = lane;
    const float* src = (wv < 2) ? xb : hb;
    const int cbase = (wv & 2) ? 64 : 0;
    #pragma unroll
    for (int it = 0; it < 8; ++it) {
      int c0 = wv * 32 + it * 4;
      s16x4 vhi, vlo;
      #pragma unroll
      for (int j = 0; j < 4; ++j) {
        int c = c0 + j;
        float v = src[(c - cbase) * L_TOT + l];
        short hi = f2bf(v);
        vhi[j] = hi;
        vlo[j] = f2bf(v - bf2f(hi));
      }
      int idx = xt_idx(l, c0);  // c0 % 4 == 0, stays inside one 16B slot half
      *(s16x4*)&xt_hi[idx] = vhi;
      *(s16x4*)&xt_lo[idx] = vlo;
    }
  }
  __syncthreads();

  // Fragment loaders.
  auto ldA = [&](const short* wb, int wrow0, int kt) -> s16x8 {
    return *(const s16x8*)&wb[(wrow0 + rA) * 128 + kt * 32 + g8];
  };
  auto ldBx = [&](const short* sb, int lt, int kt) -> s16x8 {
    int l = lt * 16 + rA;
    int c = kt * 32 + g8;
    return *(const s16x8*)&sb[l * 128 + ((((c >> 3) ^ l) & 15) << 3)];
  };
  auto ldBh = [&](const short* sb, int lt, int kt) -> s16x8 {
    int l = lt * 16 + rA;
    int c = kt * 32 + g8;
    return *(const s16x8*)&sb[l * 64 + ((((c >> 3) ^ l) & 7) << 3)];
  };

  f32x4 accR[4], accU[4], accN[4];
  #pragma unroll
  for (int i = 0; i < 4; ++i) { accR[i] = 0.0f; accU[i] = 0.0f; accN[i] = 0.0f; }

  // ---- Phase 2: R and U gates, K=128, split-bf16 (3 MFMAs per hi/lo pair) ----
  #pragma unroll
  for (int kt = 0; kt < 4; ++kt) {
    s16x8 arh = ldA(whi, wv * 16, kt);
    s16x8 arl = ldA(wlo, wv * 16, kt);
    s16x8 auh = ldA(whi, 64 + wv * 16, kt);
    s16x8 aul = ldA(wlo, 64 + wv * 16, kt);
    #pragma unroll
    for (int lt = 0; lt < 4; ++lt) {
      s16x8 bh = ldBx(xt_hi, lt, kt);
      s16x8 bl = ldBx(xt_lo, lt, kt);
      accR[lt] = MFMA(arh, bh, accR[lt]);
      accR[lt] = MFMA(arl, bh, accR[lt]);
      accR[lt] = MFMA(arh, bl, accR[lt]);
      accU[lt] = MFMA(auh, bh, accU[lt]);
      accU[lt] = MFMA(aul, bh, accU[lt]);
      accU[lt] = MFMA(auh, bl, accU[lt]);
    }
  }

  // ---- Phase 3: N partial, W_h[:, 0:64] @ input ----
  #pragma unroll
  for (int kt = 0; kt < 2; ++kt) {
    s16x8 anh = ldA(whi, 128 + wv * 16, kt);
    s16x8 anl = ldA(wlo, 128 + wv * 16, kt);
    #pragma unroll
    for (int lt = 0; lt < 4; ++lt) {
      s16x8 bh = ldBx(xt_hi, lt, kt);
      s16x8 bl = ldBx(xt_lo, lt, kt);
      accN[lt] = MFMA(anh, bh, accN[lt]);
      accN[lt] = MFMA(anl, bh, accN[lt]);
      accN[lt] = MFMA(anh, bl, accN[lt]);
    }
  }

  // ---- Phase 4: r = sigmoid(accR + b_r); write h*r to LDS (hi/lo split) ----
  float brv[4];
  #pragma unroll
  for (int r = 0; r < 4; ++r) brv[r] = pbr[wv * 16 + ((lane >> 4) << 2) + r];

  float hcache[4][4];
  #pragma unroll
  for (int lt = 0; lt < 4; ++lt) {
    int l = lt * 16 + rA;
    #pragma unroll
    for (int r = 0; r < 4; ++r) {
      int o = wv * 16 + ((lane >> 4) << 2) + r;  // C/D layout row
      int xi = xt_idx(l, 64 + o);
      float hval = bf2f(xt_hi[xi]) + bf2f(xt_lo[xi]);
      hcache[lt][r] = hval;
      float rv = sigmoid_f(accR[lt][r] + brv[r]);
      float hr = hval * rv;
      short hi = f2bf(hr);
      int hidx = hr_idx(l, o);
      hr_hi[hidx] = hi;
      hr_lo[hidx] = f2bf(hr - bf2f(hi));
    }
  }
  __syncthreads();

  // ---- Phase 5: N += W_h[:, 64:128] @ (h*r) ----
  #pragma unroll
  for (int kt = 0; kt < 2; ++kt) {
    s16x8 anh = ldA(whi, 128 + wv * 16, 2 + kt);
    s16x8 anl = ldA(wlo, 128 + wv * 16, 2 + kt);
    #pragma unroll
    for (int lt = 0; lt < 4; ++lt) {
      s16x8 bh = ldBh(hr_hi, lt, kt);
      s16x8 bl = ldBh(hr_lo, lt, kt);
      accN[lt] = MFMA(anh, bh, accN[lt]);
      accN[lt] = MFMA(anl, bh, accN[lt]);
      accN[lt] = MFMA(anh, bl, accN[lt]);
    }
  }

  // ---- Phase 6: epilogue: out = (1-u)*tanh(n) + u*h ----
  float buv[4], bhv[4];
  #pragma unroll
  for (int r = 0; r < 4; ++r) {
    int o = wv * 16 + ((lane >> 4) << 2) + r;
    buv[r] = pbu[o];
    bhv[r] = pbh[o];
  }
  #pragma unroll
  for (int lt = 0; lt < 4; ++lt) {
    int l = lt * 16 + rA;
    #pragma unroll
    for (int r = 0; r < 4; ++r) {
      int o = wv * 16 + ((lane >> 4) << 2) + r;
      float u = sigmoid_f(accU[lt][r] + buv[r]);
      float nh = tanh_f(accN[lt][r] + bhv[r]);
      out[((size_t)b * 64 + o) * L_TOT + l0 + l] =
          (1.0f - u) * nh + u * hcache[lt][r];
    }
  }
}

extern "C" void kernel_launch(void* const* d_in, const int* in_sizes, int n_in,
                              void* d_out, int out_size, void* d_ws, size_t ws_size,
                              hipStream_t stream) {
  (void)in_sizes; (void)n_in; (void)out_size; (void)ws_size;
  const float* xin = (const float*)d_in[0];
  const float* hin = (const float*)d_in[1];
  const float* Wr  = (const float*)d_in[2];
  const float* pbr = (const float*)d_in[3];
  const float* Wu  = (const float*)d_in[4];
  const float* pbu = (const float*)d_in[5];
  const float* Wh  = (const float*)d_in[6];
  const float* pbh = (const float*)d_in[7];
  float* out = (float*)d_out;

  short* whi = (short*)d_ws;
  short* wlo = whi + 192 * 128;

  hipLaunchKernelGGL(prep_weights, dim3(96), dim3(256), 0, stream,
                     Wr, Wu, Wh, whi, wlo);
  dim3 grid(L_TOT / LT, 32);
  hipLaunchKernelGGL(gru_main, grid, dim3(256), 0, stream,
                     xin, hin, whi, wlo, pbr, pbu, pbh, out);
}